// Round 8
// baseline (374.977 us; speedup 1.0000x reference)
//
// R16: slc_swa_v14 — block-level sel/swa split: grid 8192 x 64thr, phase =
// blockIdx&1 (block-uniform branch; no cross-wave LDS/barriers — avoids the
// v11 failure shape). Phase0 = v13 cmp+top8+sel verbatim -> fp32 obufA
// (overlays dead WT region); phase1 = v13 swa verbatim -> bf16 obuf.
// merge_ob sums A+B into obuf before cast_tr(Wo) reuses WT. Halves per-wave
// serial tiles, doubles resident waves. GEMMs/casts/rope unchanged (R15).
#include <hip/hip_runtime.h>
#include <hip/hip_bf16.h>
#include <math.h>

#define T_SEQ 1024
#define NH    64
#define NKV   4
#define DH    64
#define GQ    16
#define BSZ   64
#define NBLK  16
#define SSEL  8
#define WWIN  512
#define SCL   0.125f
#define SCL2  0.18033688011112042f   /* SCL * log2(e) */
#define NEGF  -1e30f
#define KVGS  768

typedef float  floatx4 __attribute__((ext_vector_type(4)));
typedef short  shortx8 __attribute__((ext_vector_type(8)));
typedef short  shortx4 __attribute__((ext_vector_type(4)));

__device__ __forceinline__ ushort f2bf(float f) {
  union { float f; unsigned u; } v; v.f = f;
  unsigned r = v.u + 0x7FFF + ((v.u >> 16) & 1);
  return (ushort)(r >> 16);
}
__device__ __forceinline__ float bf2f(ushort u) {
  union { unsigned u; float f; } v; v.u = ((unsigned)u) << 16;
  return v.f;
}
__device__ __forceinline__ void gld_lds16(const ushort* g, ushort* l) {
  __builtin_amdgcn_global_load_lds((const __attribute__((address_space(1))) void*)g,
                                   (__attribute__((address_space(3))) void*)l, 16, 0, 0);
}
__device__ __forceinline__ shortx4 u2s4(uint lo, uint hi) {
  union { uint2 u; shortx4 s; } c; c.u = make_uint2(lo, hi); return c.s;
}
__device__ __forceinline__ uint cvtpk(float lo, float hi) {
  uint r;
  asm("v_cvt_pk_bf16_f32 %0, %1, %2" : "=v"(r) : "v"(lo), "v"(hi));
  return r;
}
__device__ __forceinline__ float fexp2(float x) { return __builtin_amdgcn_exp2f(x); }
__device__ __forceinline__ shortx4 lo4(shortx8 v) {
  return __builtin_shufflevector(v, v, 0, 1, 2, 3);
}
__device__ __forceinline__ shortx4 hi4(shortx8 v) {
  return __builtin_shufflevector(v, v, 4, 5, 6, 7);
}
__device__ __forceinline__ floatx4 mfma32(shortx8 a, shortx8 b, floatx4 c) {
  return __builtin_amdgcn_mfma_f32_16x16x32_bf16(a, b, c, 0, 0, 0);
}
__device__ __forceinline__ floatx4 mfma16(shortx4 a, shortx4 b, floatx4 c) {
#if __has_builtin(__builtin_amdgcn_mfma_f32_16x16x16bf16_1k)
  return __builtin_amdgcn_mfma_f32_16x16x16bf16_1k(a, b, c, 0, 0, 0);
#else
  asm volatile("v_mfma_f32_16x16x16_bf16 %0, %1, %2, %0\n\ts_nop 7\n\ts_nop 7"
               : "+v"(c) : "v"(a), "v"(b));
  return c;
#endif
}

// ---------------- cast fp32 -> bf16 ----------------
__global__ void cast_x(const float* __restrict__ in, ushort* __restrict__ out, int n4) {
  int i = blockIdx.x * blockDim.x + threadIdx.x;
  if (i >= n4) return;
  float4 f = ((const float4*)in)[i];
  ushort4 u;
  u.x = f2bf(f.x); u.y = f2bf(f.y); u.z = f2bf(f.z); u.w = f2bf(f.w);
  ((ushort4*)out)[i] = u;
}

// ---------------- cast+transpose fp32 [K][N] -> bf16 [N][K] ----------------
__global__ __launch_bounds__(256) void cast_tr(const float* __restrict__ in,
                                               ushort* __restrict__ out, int K, int N) {
  __shared__ float tile[32][33];
  int k0 = blockIdx.y * 32, n0 = blockIdx.x * 32;
  int tx = threadIdx.x & 31, ty = threadIdx.x >> 5;
#pragma unroll
  for (int r = 0; r < 32; r += 8)
    tile[ty + r][tx] = in[(size_t)(k0 + ty + r) * N + n0 + tx];
  __syncthreads();
#pragma unroll
  for (int r = 0; r < 32; r += 8)
    out[(size_t)(n0 + ty + r) * K + k0 + tx] = f2bf(tile[tx][ty + r]);
}

// ---------------- fused Wk|Wv|Wg cast+transpose into Wkvg[704][2048] ----------------
__global__ __launch_bounds__(256) void cast_tr_kvg(const float* __restrict__ Wk,
                                                   const float* __restrict__ Wv,
                                                   const float* __restrict__ Wg,
                                                   ushort* __restrict__ out) {
  __shared__ float tile[32][33];
  int n0 = blockIdx.x * 32;           // 0..672
  int k0 = blockIdx.y * 32;
  const float* src; int coff, Nsrc;
  if (n0 < 256)      { src = Wk; coff = n0;       Nsrc = 256; }
  else if (n0 < 512) { src = Wv; coff = n0 - 256; Nsrc = 256; }
  else               { src = Wg; coff = n0 - 512; Nsrc = 192; }
  int tx = threadIdx.x & 31, ty = threadIdx.x >> 5;
#pragma unroll
  for (int r = 0; r < 32; r += 8)
    tile[ty + r][tx] = src[(size_t)(k0 + ty + r) * Nsrc + coff + tx];
  __syncthreads();
#pragma unroll
  for (int r = 0; r < 32; r += 8)
    out[(size_t)(n0 + ty + r) * 2048 + k0 + tx] = f2bf(tile[tx][ty + r]);
}

// ===== 128x128 / BK64 bf16 GEMM core (m97 structure), 256 thr, 4 waves =====
#define GEMM128_BODY(EPILOGUE)                                                 \
  __shared__ ushort As[128 * 64];                                              \
  __shared__ ushort Bs[128 * 64];                                              \
  int tid = threadIdx.x, wv = tid >> 6, lane = tid & 63;                       \
  int m0 = blockIdx.y * 128, n0 = blockIdx.x * 128;                            \
  int l15 = lane & 15, quad = lane >> 4;                                       \
  int wr = wv >> 1, wc = wv & 1;                                               \
  floatx4 acc[4][4];                                                           \
  _Pragma("unroll")                                                            \
  for (int i = 0; i < 4; ++i)                                                  \
    _Pragma("unroll")                                                          \
    for (int j = 0; j < 4; ++j) acc[i][j] = (floatx4){0.f, 0.f, 0.f, 0.f};     \
  for (int k0 = kbeg; k0 < kend; k0 += 64) {                                   \
    _Pragma("unroll")                                                          \
    for (int it = 0; it < 4; ++it) {                                           \
      int c = it * 4 + wv;                                                     \
      int ci = c * 64 + lane;                                                  \
      gld_lds16(A + (size_t)(m0 + (ci >> 3)) * K + k0 + (ci & 7) * 8,          \
                As + (size_t)c * 512);                                         \
      gld_lds16(Bt + (size_t)(n0 + (ci >> 3)) * K + k0 + (ci & 7) * 8,         \
                Bs + (size_t)c * 512);                                         \
    }                                                                          \
    __syncthreads();                                                           \
    _Pragma("unroll")                                                          \
    for (int ks = 0; ks < 2; ++ks) {                                           \
      shortx8 af[4], bf[4];                                                    \
      _Pragma("unroll")                                                        \
      for (int i = 0; i < 4; ++i)                                              \
        af[i] = *(const shortx8*)&As[(wr * 64 + i * 16 + l15) * 64 + ks * 32 + quad * 8]; \
      _Pragma("unroll")                                                        \
      for (int j = 0; j < 4; ++j)                                              \
        bf[j] = *(const shortx8*)&Bs[(wc * 64 + j * 16 + l15) * 64 + ks * 32 + quad * 8]; \
      _Pragma("unroll")                                                        \
      for (int i = 0; i < 4; ++i)                                              \
        _Pragma("unroll")                                                      \
        for (int j = 0; j < 4; ++j)                                            \
          acc[i][j] = mfma32(af[i], bf[j], acc[i][j]);                         \
    }                                                                          \
    __syncthreads();                                                           \
  }                                                                            \
  _Pragma("unroll")                                                            \
  for (int i = 0; i < 4; ++i)                                                  \
    _Pragma("unroll")                                                          \
    for (int j = 0; j < 4; ++j)                                                \
      _Pragma("unroll")                                                        \
      for (int r = 0; r < 4; ++r) {                                            \
        size_t row = (size_t)(m0 + wr * 64 + i * 16 + quad * 4 + r);           \
        size_t col = (size_t)(n0 + wc * 64 + j * 16 + l15);                    \
        EPILOGUE;                                                              \
      }

__global__ __launch_bounds__(256) void gemm128_f32at(const ushort* __restrict__ A,
                                                     const ushort* __restrict__ Bt,
                                                     float* __restrict__ C,
                                                     int M, int N, int K, int klen) {
  int kbeg = blockIdx.z * klen, kend = kbeg + klen;
  GEMM128_BODY(atomicAdd(&C[row * N + col], acc[i][j][r]))
}

__global__ __launch_bounds__(256) void gemm128_bf16c(const ushort* __restrict__ A,
                                                     const ushort* __restrict__ Bt,
                                                     ushort* __restrict__ C,
                                                     int M, int N, int K) {
  int kbeg = 0, kend = K;
  GEMM128_BODY(C[row * N + col] = f2bf(acc[i][j][r]))
}

// ---------------- RoPE on bf16 q ----------------
__global__ void rope_bq(ushort* __restrict__ qb) {
  int idx = blockIdx.x * blockDim.x + threadIdx.x;
  if (idx >= T_SEQ * NH * 32) return;
  int i = idx & 31;
  int h = (idx >> 5) & 63;
  int t = idx / (32 * NH);
  float inv = __expf(-(float)i * 0.28782313662425575f);
  float f = (float)t * inv;
  float s, c;
  __sincosf(f, &s, &c);
  ushort* p = qb + ((size_t)t * NH + h) * DH;
  float x1 = bf2f(p[i]), x2 = bf2f(p[i + 32]);
  p[i]      = f2bf(x1 * c - x2 * s);
  p[i + 32] = f2bf(x1 * s + x2 * c);
}

// ---------------- RoPE on fp32 k + write bf16 kb (fused) ----------------
__global__ void rope_kb(float* __restrict__ kvg, ushort* __restrict__ kb) {
  int idx = blockIdx.x * blockDim.x + threadIdx.x;
  if (idx >= T_SEQ * NKV * 32) return;
  int i = idx & 31;
  int h = (idx >> 5) & 3;
  int t = idx / (32 * NKV);
  float inv = __expf(-(float)i * 0.28782313662425575f);
  float f = (float)t * inv;
  float s, c;
  __sincosf(f, &s, &c);
  float* p = kvg + (size_t)t * KVGS + h * DH;
  float x1 = p[i], x2 = p[i + 32];
  float r1 = x1 * c - x2 * s, r2 = x1 * s + x2 * c;
  p[i] = r1; p[i + 32] = r2;
  ushort* kp = kb + (size_t)t * 256 + h * DH;
  kp[i] = f2bf(r1); kp[i + 32] = f2bf(r2);
}

// ---------------- V -> bf16 transposed+permuted vtg[d(256)][t'(1024)] ----------
__global__ __launch_bounds__(256) void vt_tr(const float* __restrict__ kvg,
                                             ushort* __restrict__ vtg) {
  __shared__ float tile[32][33];
  int t0 = blockIdx.x * 32, d0 = blockIdx.y * 32;
  int tx = threadIdx.x & 31, ty = threadIdx.x >> 5;
#pragma unroll
  for (int r = 0; r < 32; r += 8)
    tile[ty + r][tx] = kvg[(size_t)(t0 + ty + r) * KVGS + 256 + d0 + tx];
  __syncthreads();
  int txn = (tx & 3) | ((tx & 0x0C) << 1) | ((tx & 0x10) >> 2);   // within-32 perm
#pragma unroll
  for (int r = 0; r < 32; r += 8)
    vtg[(size_t)(d0 + ty + r) * T_SEQ + t0 + txn] = f2bf(tile[tx][ty + r]);
}

// ---------------- block means -> bf16 kcb[n][256], vcbT[d(256)][n(16)] ----------------
__global__ void cmp_mean(const float* __restrict__ kvg,
                         ushort* __restrict__ kcb, ushort* __restrict__ vcbT) {
  int idx = blockIdx.x * blockDim.x + threadIdx.x;
  if (idx >= NBLK * NKV * DH) return;
  int d = idx & 63, hkv = (idx >> 6) & 3, n = idx >> 8;
  float sk = 0.f, sv = 0.f;
  for (int j = 0; j < BSZ; ++j) {
    size_t row = (size_t)(n * BSZ + j) * KVGS;
    sk += kvg[row + hkv * DH + d];
    sv += kvg[row + 256 + hkv * DH + d];
  }
  kcb[idx] = f2bf(sk * (1.0f / 64.0f));
  vcbT[(size_t)(hkv * 64 + d) * 16 + n] = f2bf(sv * (1.0f / 64.0f));
}

// ---------------- merge: obuf = bf16(obufA_f32 + obuf_bf16) ----------------
__global__ void merge_ob(const float* __restrict__ a, ushort* __restrict__ b, int n4) {
  int i = blockIdx.x * blockDim.x + threadIdx.x;
  if (i >= n4) return;
  float4 fa = ((const float4*)a)[i];
  ushort4 ub = ((const ushort4*)b)[i];
  ushort4 o;
  o.x = f2bf(fa.x + bf2f(ub.x));
  o.y = f2bf(fa.y + bf2f(ub.y));
  o.z = f2bf(fa.z + bf2f(ub.z));
  o.w = f2bf(fa.w + bf2f(ub.w));
  ((ushort4*)b)[i] = o;
}

// ------- fused cmp + topk + slc | swa (v14): phase-split single-wave blocks ----
__global__ __launch_bounds__(64) void slc_swa_v14(
    const ushort* __restrict__ qb, const float* __restrict__ kvg,
    const ushort* __restrict__ kb, const ushort* __restrict__ vtg,
    const ushort* __restrict__ kcb, const ushort* __restrict__ vcbT,
    float* __restrict__ obufA, ushort* __restrict__ obufB) {
  int lane = threadIdx.x;
  int bb = blockIdx.x;
  int phase = bb & 1;                             // block-uniform
  int bb2 = bb >> 1;
  int bb4 = bb2 >> 2;                             // v13's balanced t-map
  int u = (bb4 & 255) * 4 + (bb4 >> 8);
  int t = (u & 1) ? (T_SEQ - 1 - (u >> 1)) : (u >> 1);
  int hkv = bb2 & 3;
  int l15 = lane & 15, quad = lane >> 4;
  const float INF = __builtin_inff();

  const ushort* qrow = qb + ((size_t)t * NH + hkv * GQ + l15) * DH;
  shortx8 qf0 = *(const shortx8*)(qrow + quad * 8);
  shortx8 qf1 = *(const shortx8*)(qrow + 32 + quad * 8);

  int nv = (t >= 63) ? (((t - 63) >> 6) + 1) : 0;
  int cur = t >> 6;

  const float* gp = kvg + (size_t)t * KVGS + 512 + (hkv * GQ + l15) * 3;
  const ushort* kbase = kb + hkv * 64;
  const ushort* vbase = vtg + (size_t)hkv * 64 * T_SEQ;

  // ===== shared online-softmax tile machinery (v13-verbatim) =====
  float m_, lp;
  floatx4 o_[4];

  auto do_tile = [&](int pos0, bool is_swa) {
    floatx4 dk[4];
#pragma unroll
    for (int kt = 0; kt < 4; ++kt) {
      const ushort* kr = &kbase[(size_t)(pos0 + kt * 16 + l15) * 256];
      shortx8 kf0 = *(const shortx8*)(kr + quad * 8);
      shortx8 kf1 = *(const shortx8*)(kr + 32 + quad * 8);
      floatx4 d = {0.f, 0.f, 0.f, 0.f};
      d = mfma32(kf0, qf0, d);           // rows = key, cols = head
      d = mfma32(kf1, qf1, d);
      dk[kt] = d;
    }
    float ymax = NEGF;
#pragma unroll
    for (int kt = 0; kt < 4; ++kt)
#pragma unroll
      for (int r = 0; r < 4; ++r) {
        int key = pos0 + kt * 16 + quad * 4 + r;
        bool valid = (key <= t) && (!is_swa || (key >= t - (WWIN - 1)));
        float y = valid ? dk[kt][r] * SCL2 : NEGF;
        dk[kt][r] = y;
        ymax = fmaxf(ymax, y);
      }
    if (__any(ymax > m_ + 8.f)) {        // rare: first tile + genuine growth
      float mx = fmaxf(ymax, __shfl_xor(ymax, 16, 64));
      mx = fmaxf(mx, __shfl_xor(mx, 32, 64));
      mx = fmaxf(m_, mx);
      float al = fexp2(m_ - mx);
      m_ = mx;
      lp *= al;
#pragma unroll
      for (int dt = 0; dt < 4; ++dt) o_[dt] = o_[dt] * al;
    }
    uint pk[8];
    float ls = 0.f;
#pragma unroll
    for (int kt = 0; kt < 4; ++kt) {
      float e0 = fexp2(dk[kt][0] - m_);
      float e1 = fexp2(dk[kt][1] - m_);
      float e2 = fexp2(dk[kt][2] - m_);
      float e3 = fexp2(dk[kt][3] - m_);
      ls += (e0 + e1) + (e2 + e3);
      pk[kt * 2]     = cvtpk(e0, e1);
      pk[kt * 2 + 1] = cvtpk(e2, e3);
    }
    lp += ls;                            // lane-local partial (own 16 keys)
#pragma unroll
    for (int dt = 0; dt < 4; ++dt) {
      const ushort* vr = &vbase[(size_t)(dt * 16 + l15) * T_SEQ + pos0 + quad * 8];
      shortx8 vA = *(const shortx8*)vr;          // kt0 | kt1 frags
      shortx8 vB = *(const shortx8*)(vr + 32);   // kt2 | kt3 frags
      o_[dt] = mfma16(lo4(vA), u2s4(pk[0], pk[1]), o_[dt]);
      o_[dt] = mfma16(hi4(vA), u2s4(pk[2], pk[3]), o_[dt]);
      o_[dt] = mfma16(lo4(vB), u2s4(pk[4], pk[5]), o_[dt]);
      o_[dt] = mfma16(hi4(vB), u2s4(pk[6], pk[7]), o_[dt]);
    }
  };

  floatx4 fin[4];   // fin[dt][r]: head=l15, d = dt*16 + quad*4 + r

  if (phase == 0) {
    // ============ cmp + top8 + sel (v13-verbatim) ============
    float g_cmp = 1.f / (1.f + __expf(-gp[0]));
    float g_slc = 1.f / (1.f + __expf(-gp[1]));
    float timp = 0.f;
    if (nv > 0) {
      const ushort* kcp = kcb + l15 * 256 + hkv * 64 + quad * 8;
      shortx8 kcf0 = *(const shortx8*)kcp;
      shortx8 kcf1 = *(const shortx8*)(kcp + 32);
      floatx4 dc = {0.f, 0.f, 0.f, 0.f};
      dc = mfma32(kcf0, qf0, dc);        // rows = block n, cols = head
      dc = mfma32(kcf1, qf1, dc);
      float sv[4];
      float mx = NEGF;
#pragma unroll
      for (int r = 0; r < 4; ++r) {
        int n = quad * 4 + r;
        sv[r] = (n < nv) ? dc[r] * SCL2 : NEGF;
        mx = fmaxf(mx, sv[r]);
      }
      mx = fmaxf(mx, __shfl_xor(mx, 16, 64));
      mx = fmaxf(mx, __shfl_xor(mx, 32, 64));
      float pv[4];
      float su = 0.f;
#pragma unroll
      for (int r = 0; r < 4; ++r) { pv[r] = fexp2(sv[r] - mx); su += pv[r]; }
      su += __shfl_xor(su, 16, 64);
      su += __shfl_xor(su, 32, 64);
      float isu = 1.f / su;
      float pn[4];
#pragma unroll
      for (int r = 0; r < 4; ++r) pn[r] = pv[r] * isu;
      float ir[4] = {pn[0], pn[1], pn[2], pn[3]};
#pragma unroll
      for (int r = 0; r < 4; ++r)
#pragma unroll
        for (int msk = 1; msk < 16; msk <<= 1) ir[r] += __shfl_xor(ir[r], msk, 64);
      int gidx = ((l15 >> 2) << 4);
      float u0 = __shfl(ir[0], gidx, 64);
      float u1 = __shfl(ir[1], gidx, 64);
      float u2 = __shfl(ir[2], gidx, 64);
      float u3 = __shfl(ir[3], gidx, 64);
      float a01 = (l15 & 1) ? u1 : u0;
      float a23 = (l15 & 1) ? u3 : u2;
      timp = (l15 & 2) ? a23 : a01;
      uint plo = cvtpk(pn[0] * g_cmp, pn[1] * g_cmp);
      uint phi = cvtpk(pn[2] * g_cmp, pn[3] * g_cmp);
      shortx4 pb = u2s4(plo, phi);
#pragma unroll
      for (int dt = 0; dt < 4; ++dt) {
        shortx4 va = *(const shortx4*)&vcbT[(size_t)(hkv * 64 + dt * 16 + l15) * 16 + quad * 4];
        floatx4 z = {0.f, 0.f, 0.f, 0.f};
        fin[dt] = mfma16(va, pb, z);
      }
    } else {
#pragma unroll
      for (int dt = 0; dt < 4; ++dt) fin[dt] = (floatx4){0.f, 0.f, 0.f, 0.f};
    }
    // top-8 by rank
    float tval;
    if (l15 > cur)                   tval = -INF;
    else if (l15 == 0 || l15 == cur) tval = INF;
    else                             tval = timp;
    int rank = 0;
#pragma unroll
    for (int d = 1; d < 16; ++d) {
      int io = (l15 + d) & 15;
      float vo = __shfl(tval, (lane & 48) | io, 64);
      if (vo > tval || (vo == tval && io < l15)) ++rank;
    }
    unsigned long long bal = __ballot(rank < 8 && tval > -INF);
    uint ms = (uint)bal & 0xFFFFu;
    // selection tiles
    m_ = NEGF; lp = 0.f;
#pragma unroll
    for (int dt = 0; dt < 4; ++dt) o_[dt] = (floatx4){0.f, 0.f, 0.f, 0.f};
    while (ms) {
      int b = __ffs(ms) - 1;
      ms &= ms - 1;
      do_tile(b * BSZ, false);
    }
    float lt = lp;
    lt += __shfl_xor(lt, 16, 64);
    lt += __shfl_xor(lt, 32, 64);
    float inv = g_slc / lt;
#pragma unroll
    for (int dt = 0; dt < 4; ++dt) fin[dt] += o_[dt] * inv;
    // write fp32 partial
    float* opA = obufA + (size_t)t * 4096 + (size_t)(hkv * GQ + l15) * 64 + quad * 4;
#pragma unroll
    for (int dt = 0; dt < 4; ++dt)
      *(floatx4*)(opA + dt * 16) = fin[dt];
  } else {
    // ==================== swa (v13-verbatim) ====================
    float g_swa = 1.f / (1.f + __expf(-gp[2]));
    m_ = NEGF; lp = 0.f;
#pragma unroll
    for (int dt = 0; dt < 4; ++dt) o_[dt] = (floatx4){0.f, 0.f, 0.f, 0.f};
    int lo = t - (WWIN - 1); if (lo < 0) lo = 0;
#pragma unroll 1
    for (int b = lo >> 6; b <= cur; ++b) do_tile(b * BSZ, true);
    float lt = lp;
    lt += __shfl_xor(lt, 16, 64);
    lt += __shfl_xor(lt, 32, 64);
    float inv = g_swa / lt;
#pragma unroll
    for (int dt = 0; dt < 4; ++dt) fin[dt] = o_[dt] * inv;
    // write bf16 partial
    ushort* op = obufB + (size_t)t * 4096 + (size_t)(hkv * GQ + l15) * 64 + quad * 4;
#pragma unroll
    for (int dt = 0; dt < 4; ++dt) {
      uint w0 = cvtpk(fin[dt][0], fin[dt][1]);
      uint w1 = cvtpk(fin[dt][2], fin[dt][3]);
      *(uint2*)(op + dt * 16) = make_uint2(w0, w1);
    }
  }
}

extern "C" void kernel_launch(void* const* d_in, const int* in_sizes, int n_in,
                              void* d_out, int out_size, void* d_ws, size_t ws_size,
                              hipStream_t stream) {
  const float* x  = (const float*)d_in[0];
  const float* Wq = (const float*)d_in[1];
  const float* Wk = (const float*)d_in[2];
  const float* Wv = (const float*)d_in[3];
  const float* Wg = (const float*)d_in[4];
  const float* Wo = (const float*)d_in[5];
  float* out = (float*)d_out;

  char* p = (char*)d_ws;
  ushort* xb    = (ushort*)p;  p += (size_t)1024 * 2048 * 2;
  ushort* WT    = (ushort*)p;  p += (size_t)4096 * 2048 * 2;   // WqT / obufA / WoT
  ushort* Wkvg  = (ushort*)p;  p += (size_t)768  * 2048 * 2;
  ushort* qbh   = (ushort*)p;  p += (size_t)1024 * 4096 * 2;
  float*  kvg   = (float*)p;   p += (size_t)1024 * KVGS * 4;
  ushort* obuf  = (ushort*)p;  p += (size_t)1024 * 4096 * 2;
  ushort* kcb   = (ushort*)p;  p += (size_t)4096 * 2;
  ushort* vcbT  = (ushort*)p;  p += (size_t)4096 * 2;
  ushort* kb    = (ushort*)p;  p += (size_t)1024 * 256 * 2;
  ushort* vtg   = (ushort*)p;  p += (size_t)256 * 1024 * 2;
  float* obufA  = (float*)WT;  // WT dead between q-proj GEMM and cast_tr(Wo)

  hipMemsetAsync(Wkvg + (size_t)704 * 2048, 0, (size_t)64 * 2048 * 2, stream);
  hipMemsetAsync(kvg, 0, (size_t)1024 * KVGS * 4, stream);     // split-K target

  cast_x<<<2048, 256, 0, stream>>>(x, xb, 1024 * 2048 / 4);
  cast_tr<<<dim3(4096 / 32, 2048 / 32), 256, 0, stream>>>(Wq, WT, 2048, 4096);
  cast_tr_kvg<<<dim3(704 / 32, 2048 / 32), 256, 0, stream>>>(Wk, Wv, Wg, Wkvg);

  gemm128_bf16c<<<dim3(4096 / 128, 1024 / 128), 256, 0, stream>>>(xb, WT, qbh, 1024, 4096, 2048);
  gemm128_f32at<<<dim3(KVGS / 128, 1024 / 128, 4), 256, 0, stream>>>(xb, Wkvg, kvg,
                                                                     1024, KVGS, 2048, 512);

  rope_bq<<<(T_SEQ * NH * 32 + 255) / 256, 256, 0, stream>>>(qbh);
  rope_kb<<<(T_SEQ * NKV * 32 + 255) / 256, 256, 0, stream>>>(kvg, kb);

  vt_tr<<<dim3(T_SEQ / 32, 256 / 32), 256, 0, stream>>>(kvg, vtg);
  cmp_mean<<<(NBLK * NKV * DH + 255) / 256, 256, 0, stream>>>(kvg, kcb, vcbT);

  slc_swa_v14<<<T_SEQ * NKV * 2, 64, 0, stream>>>(qbh, kvg, kb, vtg, kcb, vcbT,
                                                  obufA, obuf);
  merge_ob<<<4096, 256, 0, stream>>>(obufA, obuf, 1024 * 4096 / 4);

  cast_tr<<<dim3(2048 / 32, 4096 / 32), 256, 0, stream>>>(Wo, WT, 4096, 2048);
  hipMemsetAsync(out, 0, (size_t)1024 * 2048 * 4, stream);     // split-K target
  gemm128_f32at<<<dim3(2048 / 128, 1024 / 128, 2), 256, 0, stream>>>(obuf, WT, out,
                                                                     1024, 2048, 4096, 2048);
}

// Round 9
// 367.478 us; speedup vs baseline: 1.0204x; 1.0204x over previous
//
// R17: slc_swa_v15 — K-stream de-amplification: kb relaid to [hkv][t][64]
// (128B rows => every K wave-load uses FULL L2 lines; was 64B-of-128B, 2x
// sector amplification on half the kernel's L2 traffic). kcb likewise ->
// [hkv][n][64]. Single-pass v13 structure restored (phase-split + merge of
// R16 dropped: cost ~7us, gained nothing). Math/schedule byte-identical to
// the passing v13; only base pointers/layouts changed. GEMMs = R15 128^2.
#include <hip/hip_runtime.h>
#include <hip/hip_bf16.h>
#include <math.h>

#define T_SEQ 1024
#define NH    64
#define NKV   4
#define DH    64
#define GQ    16
#define BSZ   64
#define NBLK  16
#define SSEL  8
#define WWIN  512
#define SCL   0.125f
#define SCL2  0.18033688011112042f   /* SCL * log2(e) */
#define NEGF  -1e30f
#define KVGS  768

typedef float  floatx4 __attribute__((ext_vector_type(4)));
typedef short  shortx8 __attribute__((ext_vector_type(8)));
typedef short  shortx4 __attribute__((ext_vector_type(4)));

__device__ __forceinline__ ushort f2bf(float f) {
  union { float f; unsigned u; } v; v.f = f;
  unsigned r = v.u + 0x7FFF + ((v.u >> 16) & 1);
  return (ushort)(r >> 16);
}
__device__ __forceinline__ float bf2f(ushort u) {
  union { unsigned u; float f; } v; v.u = ((unsigned)u) << 16;
  return v.f;
}
__device__ __forceinline__ void gld_lds16(const ushort* g, ushort* l) {
  __builtin_amdgcn_global_load_lds((const __attribute__((address_space(1))) void*)g,
                                   (__attribute__((address_space(3))) void*)l, 16, 0, 0);
}
__device__ __forceinline__ shortx4 u2s4(uint lo, uint hi) {
  union { uint2 u; shortx4 s; } c; c.u = make_uint2(lo, hi); return c.s;
}
__device__ __forceinline__ uint cvtpk(float lo, float hi) {
  uint r;
  asm("v_cvt_pk_bf16_f32 %0, %1, %2" : "=v"(r) : "v"(lo), "v"(hi));
  return r;
}
__device__ __forceinline__ float fexp2(float x) { return __builtin_amdgcn_exp2f(x); }
__device__ __forceinline__ shortx4 lo4(shortx8 v) {
  return __builtin_shufflevector(v, v, 0, 1, 2, 3);
}
__device__ __forceinline__ shortx4 hi4(shortx8 v) {
  return __builtin_shufflevector(v, v, 4, 5, 6, 7);
}
__device__ __forceinline__ floatx4 mfma32(shortx8 a, shortx8 b, floatx4 c) {
  return __builtin_amdgcn_mfma_f32_16x16x32_bf16(a, b, c, 0, 0, 0);
}
__device__ __forceinline__ floatx4 mfma16(shortx4 a, shortx4 b, floatx4 c) {
#if __has_builtin(__builtin_amdgcn_mfma_f32_16x16x16bf16_1k)
  return __builtin_amdgcn_mfma_f32_16x16x16bf16_1k(a, b, c, 0, 0, 0);
#else
  asm volatile("v_mfma_f32_16x16x16_bf16 %0, %1, %2, %0\n\ts_nop 7\n\ts_nop 7"
               : "+v"(c) : "v"(a), "v"(b));
  return c;
#endif
}

// ---------------- cast fp32 -> bf16 ----------------
__global__ void cast_x(const float* __restrict__ in, ushort* __restrict__ out, int n4) {
  int i = blockIdx.x * blockDim.x + threadIdx.x;
  if (i >= n4) return;
  float4 f = ((const float4*)in)[i];
  ushort4 u;
  u.x = f2bf(f.x); u.y = f2bf(f.y); u.z = f2bf(f.z); u.w = f2bf(f.w);
  ((ushort4*)out)[i] = u;
}

// ---------------- cast+transpose fp32 [K][N] -> bf16 [N][K] ----------------
__global__ __launch_bounds__(256) void cast_tr(const float* __restrict__ in,
                                               ushort* __restrict__ out, int K, int N) {
  __shared__ float tile[32][33];
  int k0 = blockIdx.y * 32, n0 = blockIdx.x * 32;
  int tx = threadIdx.x & 31, ty = threadIdx.x >> 5;
#pragma unroll
  for (int r = 0; r < 32; r += 8)
    tile[ty + r][tx] = in[(size_t)(k0 + ty + r) * N + n0 + tx];
  __syncthreads();
#pragma unroll
  for (int r = 0; r < 32; r += 8)
    out[(size_t)(n0 + ty + r) * K + k0 + tx] = f2bf(tile[tx][ty + r]);
}

// ---------------- fused Wk|Wv|Wg cast+transpose into Wkvg[704][2048] ----------------
__global__ __launch_bounds__(256) void cast_tr_kvg(const float* __restrict__ Wk,
                                                   const float* __restrict__ Wv,
                                                   const float* __restrict__ Wg,
                                                   ushort* __restrict__ out) {
  __shared__ float tile[32][33];
  int n0 = blockIdx.x * 32;           // 0..672
  int k0 = blockIdx.y * 32;
  const float* src; int coff, Nsrc;
  if (n0 < 256)      { src = Wk; coff = n0;       Nsrc = 256; }
  else if (n0 < 512) { src = Wv; coff = n0 - 256; Nsrc = 256; }
  else               { src = Wg; coff = n0 - 512; Nsrc = 192; }
  int tx = threadIdx.x & 31, ty = threadIdx.x >> 5;
#pragma unroll
  for (int r = 0; r < 32; r += 8)
    tile[ty + r][tx] = src[(size_t)(k0 + ty + r) * Nsrc + coff + tx];
  __syncthreads();
#pragma unroll
  for (int r = 0; r < 32; r += 8)
    out[(size_t)(n0 + ty + r) * 2048 + k0 + tx] = f2bf(tile[tx][ty + r]);
}

// ===== 128x128 / BK64 bf16 GEMM core (m97 structure), 256 thr, 4 waves =====
#define GEMM128_BODY(EPILOGUE)                                                 \
  __shared__ ushort As[128 * 64];                                              \
  __shared__ ushort Bs[128 * 64];                                              \
  int tid = threadIdx.x, wv = tid >> 6, lane = tid & 63;                       \
  int m0 = blockIdx.y * 128, n0 = blockIdx.x * 128;                            \
  int l15 = lane & 15, quad = lane >> 4;                                       \
  int wr = wv >> 1, wc = wv & 1;                                               \
  floatx4 acc[4][4];                                                           \
  _Pragma("unroll")                                                            \
  for (int i = 0; i < 4; ++i)                                                  \
    _Pragma("unroll")                                                          \
    for (int j = 0; j < 4; ++j) acc[i][j] = (floatx4){0.f, 0.f, 0.f, 0.f};     \
  for (int k0 = kbeg; k0 < kend; k0 += 64) {                                   \
    _Pragma("unroll")                                                          \
    for (int it = 0; it < 4; ++it) {                                           \
      int c = it * 4 + wv;                                                     \
      int ci = c * 64 + lane;                                                  \
      gld_lds16(A + (size_t)(m0 + (ci >> 3)) * K + k0 + (ci & 7) * 8,          \
                As + (size_t)c * 512);                                         \
      gld_lds16(Bt + (size_t)(n0 + (ci >> 3)) * K + k0 + (ci & 7) * 8,         \
                Bs + (size_t)c * 512);                                         \
    }                                                                          \
    __syncthreads();                                                           \
    _Pragma("unroll")                                                          \
    for (int ks = 0; ks < 2; ++ks) {                                           \
      shortx8 af[4], bf[4];                                                    \
      _Pragma("unroll")                                                        \
      for (int i = 0; i < 4; ++i)                                              \
        af[i] = *(const shortx8*)&As[(wr * 64 + i * 16 + l15) * 64 + ks * 32 + quad * 8]; \
      _Pragma("unroll")                                                        \
      for (int j = 0; j < 4; ++j)                                              \
        bf[j] = *(const shortx8*)&Bs[(wc * 64 + j * 16 + l15) * 64 + ks * 32 + quad * 8]; \
      _Pragma("unroll")                                                        \
      for (int i = 0; i < 4; ++i)                                              \
        _Pragma("unroll")                                                      \
        for (int j = 0; j < 4; ++j)                                            \
          acc[i][j] = mfma32(af[i], bf[j], acc[i][j]);                         \
    }                                                                          \
    __syncthreads();                                                           \
  }                                                                            \
  _Pragma("unroll")                                                            \
  for (int i = 0; i < 4; ++i)                                                  \
    _Pragma("unroll")                                                          \
    for (int j = 0; j < 4; ++j)                                                \
      _Pragma("unroll")                                                        \
      for (int r = 0; r < 4; ++r) {                                            \
        size_t row = (size_t)(m0 + wr * 64 + i * 16 + quad * 4 + r);           \
        size_t col = (size_t)(n0 + wc * 64 + j * 16 + l15);                    \
        EPILOGUE;                                                              \
      }

__global__ __launch_bounds__(256) void gemm128_f32at(const ushort* __restrict__ A,
                                                     const ushort* __restrict__ Bt,
                                                     float* __restrict__ C,
                                                     int M, int N, int K, int klen) {
  int kbeg = blockIdx.z * klen, kend = kbeg + klen;
  GEMM128_BODY(atomicAdd(&C[row * N + col], acc[i][j][r]))
}

__global__ __launch_bounds__(256) void gemm128_bf16c(const ushort* __restrict__ A,
                                                     const ushort* __restrict__ Bt,
                                                     ushort* __restrict__ C,
                                                     int M, int N, int K) {
  int kbeg = 0, kend = K;
  GEMM128_BODY(C[row * N + col] = f2bf(acc[i][j][r]))
}

// ---------------- RoPE on bf16 q ----------------
__global__ void rope_bq(ushort* __restrict__ qb) {
  int idx = blockIdx.x * blockDim.x + threadIdx.x;
  if (idx >= T_SEQ * NH * 32) return;
  int i = idx & 31;
  int h = (idx >> 5) & 63;
  int t = idx / (32 * NH);
  float inv = __expf(-(float)i * 0.28782313662425575f);
  float f = (float)t * inv;
  float s, c;
  __sincosf(f, &s, &c);
  ushort* p = qb + ((size_t)t * NH + h) * DH;
  float x1 = bf2f(p[i]), x2 = bf2f(p[i + 32]);
  p[i]      = f2bf(x1 * c - x2 * s);
  p[i + 32] = f2bf(x1 * s + x2 * c);
}

// ------- RoPE on fp32 k + write bf16 kb[hkv][t][64] (hkv-major, 128B rows) ----
__global__ void rope_kb(float* __restrict__ kvg, ushort* __restrict__ kb) {
  int idx = blockIdx.x * blockDim.x + threadIdx.x;
  if (idx >= T_SEQ * NKV * 32) return;
  int i = idx & 31;
  int h = (idx >> 5) & 3;
  int t = idx / (32 * NKV);
  float inv = __expf(-(float)i * 0.28782313662425575f);
  float f = (float)t * inv;
  float s, c;
  __sincosf(f, &s, &c);
  float* p = kvg + (size_t)t * KVGS + h * DH;
  float x1 = p[i], x2 = p[i + 32];
  float r1 = x1 * c - x2 * s, r2 = x1 * s + x2 * c;
  p[i] = r1; p[i + 32] = r2;
  ushort* kp = kb + ((size_t)h * T_SEQ + t) * 64;
  kp[i] = f2bf(r1); kp[i + 32] = f2bf(r2);
}

// ---------------- V -> bf16 transposed+permuted vtg[d(256)][t'(1024)] ----------
__global__ __launch_bounds__(256) void vt_tr(const float* __restrict__ kvg,
                                             ushort* __restrict__ vtg) {
  __shared__ float tile[32][33];
  int t0 = blockIdx.x * 32, d0 = blockIdx.y * 32;
  int tx = threadIdx.x & 31, ty = threadIdx.x >> 5;
#pragma unroll
  for (int r = 0; r < 32; r += 8)
    tile[ty + r][tx] = kvg[(size_t)(t0 + ty + r) * KVGS + 256 + d0 + tx];
  __syncthreads();
  int txn = (tx & 3) | ((tx & 0x0C) << 1) | ((tx & 0x10) >> 2);   // within-32 perm
#pragma unroll
  for (int r = 0; r < 32; r += 8)
    vtg[(size_t)(d0 + ty + r) * T_SEQ + t0 + txn] = f2bf(tile[tx][ty + r]);
}

// -------- block means -> bf16 kcb[hkv][n][64], vcbT[d(256)][n(16)] -----------
__global__ void cmp_mean(const float* __restrict__ kvg,
                         ushort* __restrict__ kcb, ushort* __restrict__ vcbT) {
  int idx = blockIdx.x * blockDim.x + threadIdx.x;
  if (idx >= NBLK * NKV * DH) return;
  int d = idx & 63, hkv = (idx >> 6) & 3, n = idx >> 8;
  float sk = 0.f, sv = 0.f;
  for (int j = 0; j < BSZ; ++j) {
    size_t row = (size_t)(n * BSZ + j) * KVGS;
    sk += kvg[row + hkv * DH + d];
    sv += kvg[row + 256 + hkv * DH + d];
  }
  kcb[(size_t)(hkv * NBLK + n) * 64 + d] = f2bf(sk * (1.0f / 64.0f));
  vcbT[(size_t)(hkv * 64 + d) * 16 + n] = f2bf(sv * (1.0f / 64.0f));
}

// ------- fused cmp + topk + slc + swa (v15): v13 math, full-line K reads ------
__global__ __launch_bounds__(64) void slc_swa_v15(
    const ushort* __restrict__ qb, const float* __restrict__ kvg,
    const ushort* __restrict__ kb, const ushort* __restrict__ vtg,
    const ushort* __restrict__ kcb, const ushort* __restrict__ vcbT,
    ushort* __restrict__ obuf) {
  int lane = threadIdx.x;
  int bb4 = blockIdx.x >> 2;                      // v10's balanced t-map
  int u = (bb4 & 255) * 4 + (bb4 >> 8);
  int t = (u & 1) ? (T_SEQ - 1 - (u >> 1)) : (u >> 1);
  int hkv = blockIdx.x & 3;
  int l15 = lane & 15, quad = lane >> 4;
  const float INF = __builtin_inff();

  const ushort* qrow = qb + ((size_t)t * NH + hkv * GQ + l15) * DH;
  shortx8 qf0 = *(const shortx8*)(qrow + quad * 8);
  shortx8 qf1 = *(const shortx8*)(qrow + 32 + quad * 8);

  int nv = (t >= 63) ? (((t - 63) >> 6) + 1) : 0;
  int cur = t >> 6;

  const float* gp = kvg + (size_t)t * KVGS + 512 + (hkv * GQ + l15) * 3;
  float g_cmp = 1.f / (1.f + __expf(-gp[0]));
  float g_slc = 1.f / (1.f + __expf(-gp[1]));
  float g_swa = 1.f / (1.f + __expf(-gp[2]));

  const ushort* kbase = kb + (size_t)hkv * T_SEQ * 64;     // [t][64], 128B rows
  const ushort* vbase = vtg + (size_t)hkv * 64 * T_SEQ;

  floatx4 fin[4];   // fin[dt][r]: head=l15, d = dt*16 + quad*4 + r
  float timp = 0.f;

  // ===== compressed attention + importance =====
  if (nv > 0) {
    const ushort* kcp = kcb + (size_t)(hkv * NBLK + l15) * 64 + quad * 8;
    shortx8 kcf0 = *(const shortx8*)kcp;
    shortx8 kcf1 = *(const shortx8*)(kcp + 32);
    floatx4 dc = {0.f, 0.f, 0.f, 0.f};
    dc = mfma32(kcf0, qf0, dc);          // rows = block n, cols = head
    dc = mfma32(kcf1, qf1, dc);
    float sv[4];
    float mx = NEGF;
#pragma unroll
    for (int r = 0; r < 4; ++r) {
      int n = quad * 4 + r;
      sv[r] = (n < nv) ? dc[r] * SCL2 : NEGF;
      mx = fmaxf(mx, sv[r]);
    }
    mx = fmaxf(mx, __shfl_xor(mx, 16, 64));
    mx = fmaxf(mx, __shfl_xor(mx, 32, 64));
    float pv[4];
    float su = 0.f;
#pragma unroll
    for (int r = 0; r < 4; ++r) { pv[r] = fexp2(sv[r] - mx); su += pv[r]; }
    su += __shfl_xor(su, 16, 64);
    su += __shfl_xor(su, 32, 64);
    float isu = 1.f / su;
    float pn[4];
#pragma unroll
    for (int r = 0; r < 4; ++r) pn[r] = pv[r] * isu;
    // importance: reduce over 16 heads (l15 lanes) within each quad
    float ir[4] = {pn[0], pn[1], pn[2], pn[3]};
#pragma unroll
    for (int r = 0; r < 4; ++r)
#pragma unroll
      for (int msk = 1; msk < 16; msk <<= 1) ir[r] += __shfl_xor(ir[r], msk, 64);
    int gidx = ((l15 >> 2) << 4);
    float u0 = __shfl(ir[0], gidx, 64);
    float u1 = __shfl(ir[1], gidx, 64);
    float u2 = __shfl(ir[2], gidx, 64);
    float u3 = __shfl(ir[3], gidx, 64);
    float a01 = (l15 & 1) ? u1 : u0;
    float a23 = (l15 & 1) ? u3 : u2;
    timp = (l15 & 2) ? a23 : a01;
    // gated cmp output
    uint plo = cvtpk(pn[0] * g_cmp, pn[1] * g_cmp);
    uint phi = cvtpk(pn[2] * g_cmp, pn[3] * g_cmp);
    shortx4 pb = u2s4(plo, phi);
#pragma unroll
    for (int dt = 0; dt < 4; ++dt) {
      shortx4 va = *(const shortx4*)&vcbT[(size_t)(hkv * 64 + dt * 16 + l15) * 16 + quad * 4];
      floatx4 z = {0.f, 0.f, 0.f, 0.f};
      fin[dt] = mfma16(va, pb, z);
    }
  } else {
#pragma unroll
    for (int dt = 0; dt < 4; ++dt) fin[dt] = (floatx4){0.f, 0.f, 0.f, 0.f};
  }

  // ===== online-softmax state (head = l15; deferred-max, partial l) =====
  float m_, lp;
  floatx4 o_[4];

  auto do_tile = [&](int pos0, bool is_swa) {
    floatx4 dk[4];
#pragma unroll
    for (int kt = 0; kt < 4; ++kt) {
      const ushort* kr = &kbase[(size_t)(pos0 + kt * 16 + l15) * 64];
      shortx8 kf0 = *(const shortx8*)(kr + quad * 8);
      shortx8 kf1 = *(const shortx8*)(kr + 32 + quad * 8);
      floatx4 d = {0.f, 0.f, 0.f, 0.f};
      d = mfma32(kf0, qf0, d);           // rows = key, cols = head
      d = mfma32(kf1, qf1, d);
      dk[kt] = d;
    }
    float ymax = NEGF;
#pragma unroll
    for (int kt = 0; kt < 4; ++kt)
#pragma unroll
      for (int r = 0; r < 4; ++r) {
        int key = pos0 + kt * 16 + quad * 4 + r;
        bool valid = (key <= t) && (!is_swa || (key >= t - (WWIN - 1)));
        float y = valid ? dk[kt][r] * SCL2 : NEGF;
        dk[kt][r] = y;
        ymax = fmaxf(ymax, y);
      }
    if (__any(ymax > m_ + 8.f)) {        // rare: first tile + genuine growth
      float mx = fmaxf(ymax, __shfl_xor(ymax, 16, 64));
      mx = fmaxf(mx, __shfl_xor(mx, 32, 64));
      mx = fmaxf(m_, mx);
      float al = fexp2(m_ - mx);
      m_ = mx;
      lp *= al;
#pragma unroll
      for (int dt = 0; dt < 4; ++dt) o_[dt] = o_[dt] * al;
    }
    uint pk[8];
    float ls = 0.f;
#pragma unroll
    for (int kt = 0; kt < 4; ++kt) {
      float e0 = fexp2(dk[kt][0] - m_);
      float e1 = fexp2(dk[kt][1] - m_);
      float e2 = fexp2(dk[kt][2] - m_);
      float e3 = fexp2(dk[kt][3] - m_);
      ls += (e0 + e1) + (e2 + e3);
      pk[kt * 2]     = cvtpk(e0, e1);
      pk[kt * 2 + 1] = cvtpk(e2, e3);
    }
    lp += ls;                            // lane-local partial (own 16 keys)
#pragma unroll
    for (int dt = 0; dt < 4; ++dt) {
      const ushort* vr = &vbase[(size_t)(dt * 16 + l15) * T_SEQ + pos0 + quad * 8];
      shortx8 vA = *(const shortx8*)vr;          // kt0 | kt1 frags
      shortx8 vB = *(const shortx8*)(vr + 32);   // kt2 | kt3 frags
      o_[dt] = mfma16(lo4(vA), u2s4(pk[0], pk[1]), o_[dt]);
      o_[dt] = mfma16(hi4(vA), u2s4(pk[2], pk[3]), o_[dt]);
      o_[dt] = mfma16(lo4(vB), u2s4(pk[4], pk[5]), o_[dt]);
      o_[dt] = mfma16(hi4(vB), u2s4(pk[6], pk[7]), o_[dt]);
    }
  };

  // ===== top-8 by rank (15 parallel shuffles), set extracted from bitmask =====
  float tval;
  if (l15 > cur)                   tval = -INF;
  else if (l15 == 0 || l15 == cur) tval = INF;
  else                             tval = timp;
  int rank = 0;
#pragma unroll
  for (int d = 1; d < 16; ++d) {
    int io = (l15 + d) & 15;
    float vo = __shfl(tval, (lane & 48) | io, 64);
    if (vo > tval || (vo == tval && io < l15)) ++rank;
  }
  unsigned long long bal = __ballot(rank < 8 && tval > -INF);
  uint msel = (uint)bal & 0xFFFFu;

  // ===== selection phase =====
  m_ = NEGF; lp = 0.f;
#pragma unroll
  for (int dt = 0; dt < 4; ++dt) o_[dt] = (floatx4){0.f, 0.f, 0.f, 0.f};
  {
    uint ms = msel;
    while (ms) {
      int b = __ffs(ms) - 1;
      ms &= ms - 1;
      do_tile(b * BSZ, false);
    }
    float lt = lp;
    lt += __shfl_xor(lt, 16, 64);
    lt += __shfl_xor(lt, 32, 64);
    float inv = g_slc / lt;
#pragma unroll
    for (int dt = 0; dt < 4; ++dt) fin[dt] += o_[dt] * inv;
  }

  // ===== sliding window =====
  m_ = NEGF; lp = 0.f;
#pragma unroll
  for (int dt = 0; dt < 4; ++dt) o_[dt] = (floatx4){0.f, 0.f, 0.f, 0.f};
  {
    int lo = t - (WWIN - 1); if (lo < 0) lo = 0;
#pragma unroll 1
    for (int b = lo >> 6; b <= cur; ++b) do_tile(b * BSZ, true);
    float lt = lp;
    lt += __shfl_xor(lt, 16, 64);
    lt += __shfl_xor(lt, 32, 64);
    float inv = g_swa / lt;
#pragma unroll
    for (int dt = 0; dt < 4; ++dt) fin[dt] += o_[dt] * inv;
  }

  // ===== write: head = l15, d = dt*16 + quad*4 + r =====
  ushort* op = obuf + (size_t)t * 4096 + (size_t)(hkv * GQ + l15) * 64 + quad * 4;
#pragma unroll
  for (int dt = 0; dt < 4; ++dt) {
    uint w0 = cvtpk(fin[dt][0], fin[dt][1]);
    uint w1 = cvtpk(fin[dt][2], fin[dt][3]);
    *(uint2*)(op + dt * 16) = make_uint2(w0, w1);
  }
}

extern "C" void kernel_launch(void* const* d_in, const int* in_sizes, int n_in,
                              void* d_out, int out_size, void* d_ws, size_t ws_size,
                              hipStream_t stream) {
  const float* x  = (const float*)d_in[0];
  const float* Wq = (const float*)d_in[1];
  const float* Wk = (const float*)d_in[2];
  const float* Wv = (const float*)d_in[3];
  const float* Wg = (const float*)d_in[4];
  const float* Wo = (const float*)d_in[5];
  float* out = (float*)d_out;

  char* p = (char*)d_ws;
  ushort* xb    = (ushort*)p;  p += (size_t)1024 * 2048 * 2;
  ushort* WT    = (ushort*)p;  p += (size_t)4096 * 2048 * 2;   // WqT, later WoT
  ushort* Wkvg  = (ushort*)p;  p += (size_t)768  * 2048 * 2;
  ushort* qbh   = (ushort*)p;  p += (size_t)1024 * 4096 * 2;
  float*  kvg   = (float*)p;   p += (size_t)1024 * KVGS * 4;
  ushort* obuf  = (ushort*)p;  p += (size_t)1024 * 4096 * 2;
  ushort* kcb   = (ushort*)p;  p += (size_t)4096 * 2;
  ushort* vcbT  = (ushort*)p;  p += (size_t)4096 * 2;
  ushort* kb    = (ushort*)p;  p += (size_t)1024 * 256 * 2;
  ushort* vtg   = (ushort*)p;  p += (size_t)256 * 1024 * 2;

  hipMemsetAsync(Wkvg + (size_t)704 * 2048, 0, (size_t)64 * 2048 * 2, stream);
  hipMemsetAsync(kvg, 0, (size_t)1024 * KVGS * 4, stream);     // split-K target

  cast_x<<<2048, 256, 0, stream>>>(x, xb, 1024 * 2048 / 4);
  cast_tr<<<dim3(4096 / 32, 2048 / 32), 256, 0, stream>>>(Wq, WT, 2048, 4096);
  cast_tr_kvg<<<dim3(704 / 32, 2048 / 32), 256, 0, stream>>>(Wk, Wv, Wg, Wkvg);

  gemm128_bf16c<<<dim3(4096 / 128, 1024 / 128), 256, 0, stream>>>(xb, WT, qbh, 1024, 4096, 2048);
  gemm128_f32at<<<dim3(KVGS / 128, 1024 / 128, 4), 256, 0, stream>>>(xb, Wkvg, kvg,
                                                                     1024, KVGS, 2048, 512);

  rope_bq<<<(T_SEQ * NH * 32 + 255) / 256, 256, 0, stream>>>(qbh);
  rope_kb<<<(T_SEQ * NKV * 32 + 255) / 256, 256, 0, stream>>>(kvg, kb);

  vt_tr<<<dim3(T_SEQ / 32, 256 / 32), 256, 0, stream>>>(kvg, vtg);
  cmp_mean<<<(NBLK * NKV * DH + 255) / 256, 256, 0, stream>>>(kvg, kcb, vcbT);

  slc_swa_v15<<<T_SEQ * NKV, 64, 0, stream>>>(qbh, kvg, kb, vtg, kcb, vcbT, obuf);

  cast_tr<<<dim3(2048 / 32, 4096 / 32), 256, 0, stream>>>(Wo, WT, 4096, 2048);
  hipMemsetAsync(out, 0, (size_t)1024 * 2048 * 4, stream);     // split-K target
  gemm128_f32at<<<dim3(2048 / 128, 1024 / 128, 2), 256, 0, stream>>>(obuf, WT, out,
                                                                     1024, 2048, 4096, 2048);
}